// Round 3
// baseline (293.825 us; speedup 1.0000x reference)
//
#include <hip/hip_runtime.h>

#define EMB 2048
#define UDIM 256
#define KTOT 2304
#define NE 64
#define TOPK 8
#define TPB 64            // tokens per block (lane = token)
#define LP 65             // LDS row stride (64+1): (lane+k)%32 banks -> 2-way, free
#define BK 64             // k-window
#define NWIN (KTOT / BK)  // 36 (h covers windows 0..31, u covers 32..35; clean split)
#define ESL 16            // experts per wave

__global__ __launch_bounds__(1024, 4)
void gate_fused(const float* __restrict__ h, const float* __restrict__ u,
                const float* __restrict__ W, const float* __restrict__ b,
                float* __restrict__ out) {
  __shared__ float xt[2][TPB * LP];  // 2 x 16.6 KB, double-buffered x window

  const int tid = threadIdx.x;
  const int lane = tid & 63;
  const int wid = __builtin_amdgcn_readfirstlane(tid >> 6);
  const int kq = wid & 3;   // k-subslice within window: [16*kq, 16*kq+16)
  const int ew = wid >> 2;  // expert slice [16*ew, 16*ew+16)
  const int tok0 = blockIdx.x * TPB;

  // staging: lane (stok, sseg) loads float4 x[tok0+stok][w*64 + sseg..+4)
  const int stok = tid >> 4;
  const int sseg = (tid & 15) * 4;

  float acc[ESL];
#pragma unroll
  for (int j = 0; j < ESL; ++j) acc[j] = 0.f;

  // stage window 0 (pure h)
  {
    float4 v = *(const float4*)(h + (size_t)(tok0 + stok) * EMB + sseg);
    float* dst = &xt[0][stok * LP + sseg];
    dst[0] = v.x; dst[1] = v.y; dst[2] = v.z; dst[3] = v.w;
  }
  __syncthreads();

  const int xbase = lane * LP + kq * 16;
  int p = 0;
  for (int w = 0; w < NWIN; ++w) {
    // prefetch next window into registers (overlaps with compute below)
    float4 v;
    if (w + 1 < NWIN) {
      const int kn = (w + 1) * BK;
      const float* src = (kn < EMB)
          ? h + (size_t)(tok0 + stok) * EMB + kn + sseg
          : u + (size_t)(tok0 + stok) * UDIM + (kn - EMB) + sseg;
      v = *(const float4*)src;
    }

    // compute window w: k in [w*64 + 16*kq, +16), experts [16*ew, +16)
    // W reads are wave-uniform -> SGPR s_load double-buffer (R2-verified).
    const float* wp = W + (size_t)(w * BK + kq * 16) * NE + ew * ESL;
    const float* xp = &xt[p][xbase];

    float4 wc[2][4];
#pragma unroll
    for (int kk = 0; kk < 2; ++kk)
#pragma unroll
      for (int j = 0; j < 4; ++j)
        wc[kk][j] = *(const float4*)(wp + kk * NE + 4 * j);

#pragma unroll
    for (int pr = 0; pr < 8; ++pr) {
      float4 wn[2][4];
      if (pr < 7) {
        const float* wq = wp + (size_t)(2 * pr + 2) * NE;
#pragma unroll
        for (int kk = 0; kk < 2; ++kk)
#pragma unroll
          for (int j = 0; j < 4; ++j)
            wn[kk][j] = *(const float4*)(wq + kk * NE + 4 * j);
      }
      const float x0 = xp[2 * pr];
      const float x1 = xp[2 * pr + 1];
#pragma unroll
      for (int j = 0; j < 4; ++j) {
        acc[4 * j + 0] = __builtin_fmaf(x0, wc[0][j].x, acc[4 * j + 0]);
        acc[4 * j + 1] = __builtin_fmaf(x0, wc[0][j].y, acc[4 * j + 1]);
        acc[4 * j + 2] = __builtin_fmaf(x0, wc[0][j].z, acc[4 * j + 2]);
        acc[4 * j + 3] = __builtin_fmaf(x0, wc[0][j].w, acc[4 * j + 3]);
      }
#pragma unroll
      for (int j = 0; j < 4; ++j) {
        acc[4 * j + 0] = __builtin_fmaf(x1, wc[1][j].x, acc[4 * j + 0]);
        acc[4 * j + 1] = __builtin_fmaf(x1, wc[1][j].y, acc[4 * j + 1]);
        acc[4 * j + 2] = __builtin_fmaf(x1, wc[1][j].z, acc[4 * j + 2]);
        acc[4 * j + 3] = __builtin_fmaf(x1, wc[1][j].w, acc[4 * j + 3]);
      }
      if (pr < 7) {
#pragma unroll
        for (int kk = 0; kk < 2; ++kk)
#pragma unroll
          for (int j = 0; j < 4; ++j) wc[kk][j] = wn[kk][j];
      }
    }

    // write prefetched window into the other buffer (disjoint from buf p)
    if (w + 1 < NWIN) {
      float* dst = &xt[1 - p][stok * LP + sseg];
      dst[0] = v.x; dst[1] = v.y; dst[2] = v.z; dst[3] = v.w;
    }
    __syncthreads();  // one barrier per window
    p ^= 1;
  }

  // ---- cross-kq reduction: slab reuses xt[0] (last window was read from xt[1])
  float* slab = xt[0];
  for (int ph = 0; ph < 4; ++ph) {
    if (kq == ph) {
      float* srow = slab + lane * LP + ew * ESL;
      if (ph == 0) {
#pragma unroll
        for (int j = 0; j < ESL; ++j) srow[j] = acc[j];
      } else {
#pragma unroll
        for (int j = 0; j < ESL; ++j) srow[j] += acc[j];
      }
    }
    __syncthreads();
  }

  // ---- epilogue: wave wid handles tokens [4*wid, 4*wid+4); lane = expert ----
  const float bias = b[lane];
#pragma unroll
  for (int tt = 0; tt < 4; ++tt) {
    const int t = wid * 4 + tt;
    float g = slab[t * LP + lane] + bias;

    // softmax over 64 lanes
    float m = g;
#pragma unroll
    for (int off = 32; off > 0; off >>= 1)
      m = fmaxf(m, __shfl_xor(m, off));
    float pexp = __expf(g - m);
    float s = pexp;
#pragma unroll
    for (int off = 32; off > 0; off >>= 1)
      s += __shfl_xor(s, off);
    const float pn = pexp / s;

    // iterative top-8 argmax; tie-break to lower index (matches top_k)
    float vv = pn;
    float topsum = 0.f;
    int sel = 0;
    for (int r = 0; r < TOPK; ++r) {
      float mv = vv;
      int mi = lane;
#pragma unroll
      for (int off = 32; off > 0; off >>= 1) {
        const float ov = __shfl_xor(mv, off);
        const int oi = __shfl_xor(mi, off);
        if (ov > mv || (ov == mv && oi < mi)) { mv = ov; mi = oi; }
      }
      topsum += mv;
      if (lane == mi) { sel = 1; vv = -1.f; }
    }

    out[(size_t)(tok0 + t) * NE + lane] =
        sel ? pn / (topsum + 1e-9f) : 0.f;
  }
}

extern "C" void kernel_launch(void* const* d_in, const int* in_sizes, int n_in,
                              void* d_out, int out_size, void* d_ws, size_t ws_size,
                              hipStream_t stream) {
  const float* h = (const float*)d_in[0];
  const float* u = (const float*)d_in[1];
  const float* W = (const float*)d_in[2];
  const float* b = (const float*)d_in[3];
  float* out = (float*)d_out;

  const int n_tokens = in_sizes[0] / EMB;  // 16384
  const int n_blocks = n_tokens / TPB;     // 256

  hipLaunchKernelGGL(gate_fused, dim3(n_blocks), dim3(1024), 0, stream,
                     h, u, W, b, out);
}